// Round 1
// baseline (457.311 us; speedup 1.0000x reference)
//
#include <hip/hip_runtime.h>
#include <hip/hip_bf16.h>

typedef unsigned int u32;
typedef unsigned short u16;

using bf16x8 = __attribute__((ext_vector_type(8))) short;
using f32x4  = __attribute__((ext_vector_type(4))) float;

// ---------------- workspace layout (bytes) ----------------
#define OFF_IN     0L        // Wt_in   [128][72]  bf16 = 18432
#define OFF_C      18432L    // Wt_c    [128][136] bf16 = 34816
#define OFF_B0     53248L    // Wt_b[8] [128][136] bf16 = 8*34816
#define OFF_SKIP   331776L   // Wt_skip [128][72]
#define OFF_SKIPC  350208L   // Wt_skipc[128][136]
#define OFF_VIEW   385024L   // Wt_view [128][40] = 10240
#define OFF_VIEWC  395264L   // Wt_viewc[128][136]
#define OFF_BIAS0  430080L   // f32[128] b_in+b_c
#define OFF_BIASSK 430592L   // f32[128] b_skip+b_skipc
#define OFF_BIASV  431104L   // f32[128] b_view+b_viewc
// total needed: 431616 bytes

// ---------------- LDS layout (bytes) ----------------
#define LDS_XE 0        // enc [64][72] bf16 (stride 144B) = 9216; reused: sigma scratch (512B), Xv [64][40] (5120B), rgb scratch @+5120 (1536B)
#define LDS_X  9216     // activations [64][136] bf16 (stride 272B) = 17408 (also holds cond_shape / cond_app at the right times)
#define LDS_W  26624    // weight window [128][136] bf16 = 34816
#define LDS_TOTAL 61440

__device__ __forceinline__ u16 f2bf(float x) {
  union { float f; u32 u; } un; un.f = x;
  u32 u = un.u;
  return (u16)((u + 0x7fffu + ((u >> 16) & 1u)) >> 16);
}
__device__ __forceinline__ u32 pack2(float a, float b) {
  return (u32)f2bf(a) | ((u32)f2bf(b) << 16);
}
__device__ __forceinline__ float sel3(float a, float b, float c, int i) {
  return i == 0 ? a : (i == 1 ? b : c);
}
// positional-encoding element e of [p(3) | {sin(p*2^l), cos(p*2^l)} blocks], zero-padded past kreal
__device__ __forceinline__ float enc_val3(float a, float b, float c, int e, int kreal) {
  if (e >= kreal) return 0.f;
  if (e < 3) return sel3(a, b, c, e);
  int t = e - 3;
  int l = t / 6;
  int rem = t - l * 6;
  int pi = rem >= 3 ? rem - 3 : rem;
  float x = sel3(a, b, c, pi) * (float)(1 << l);
  return rem < 3 ? sinf(x) : cosf(x);
}

// ---------------- prep kernel: transpose+pad+bf16 all weights into ws ----------------
__global__ void prep_kernel(
    const float* __restrict__ Win, const float* __restrict__ Wc, const float* __restrict__ Wb,
    const float* __restrict__ Wskip, const float* __restrict__ Wskipc,
    const float* __restrict__ Wview, const float* __restrict__ Wviewc,
    const float* __restrict__ bin, const float* __restrict__ bc,
    const float* __restrict__ bskip, const float* __restrict__ bskipc,
    const float* __restrict__ bview, const float* __restrict__ bviewc,
    char* __restrict__ ws) {
  int i = blockIdx.x * 256 + threadIdx.x;
  if (i >= 215424) return;
  int r = i;
  const float* src; int kpad, kreal; long dstoff;
  if (r < 9216)                    { src = Win;    kpad = 72;  kreal = 63;  dstoff = OFF_IN; }
  else if ((r -= 9216) < 17408)    { src = Wc;     kpad = 136; kreal = 128; dstoff = OFF_C; }
  else if ((r -= 17408) < 139264)  { int b = r / 17408; r -= b * 17408;
                                     src = Wb + (long)b * 16384; kpad = 136; kreal = 128;
                                     dstoff = OFF_B0 + (long)b * 34816; }
  else if ((r -= 139264) < 9216)   { src = Wskip;  kpad = 72;  kreal = 63;  dstoff = OFF_SKIP; }
  else if ((r -= 9216) < 17408)    { src = Wskipc; kpad = 136; kreal = 128; dstoff = OFF_SKIPC; }
  else if ((r -= 17408) < 5120)    { src = Wview;  kpad = 40;  kreal = 27;  dstoff = OFF_VIEW; }
  else if ((r -= 5120) < 17408)    { src = Wviewc; kpad = 136; kreal = 128; dstoff = OFF_VIEWC; }
  else {
    r -= 17408;  // 0..383  -> combined biases
    int which = r >> 7, n = r & 127;
    const float* A  = which == 0 ? bin : (which == 1 ? bskip : bview);
    const float* Bp = which == 0 ? bc  : (which == 1 ? bskipc : bviewc);
    long off = which == 0 ? OFF_BIAS0 : (which == 1 ? OFF_BIASSK : OFF_BIASV);
    *(float*)(ws + off + (long)n * 4) = A[n] + Bp[n];
    return;
  }
  int n = r / kpad, k = r - n * kpad;
  float v = (k < kreal) ? src[(long)k * 128 + n] : 0.f;
  *(u16*)(ws + dstoff + ((long)n * kpad + k) * 2) = f2bf(v);
}

// ---------------- main fused kernel ----------------
#define STAGEW(srcoff, bytes)                                                  \
  do {                                                                         \
    const char* s_ = ws + (srcoff);                                            \
    for (int o_ = tid * 16; o_ < (bytes); o_ += 4096)                          \
      *(int4*)(lds + LDS_W + o_) = *(const int4*)(s_ + o_);                    \
  } while (0)

#define ACC_INIT(bptr)                                                         \
  do {                                                                         \
    _Pragma("unroll") for (int j = 0; j < 4; ++j) {                            \
      float b_ = (bptr)[nBase + 16 * j];                                       \
      f32x4 t_ = {b_, b_, b_, b_};                                             \
      acc[0][j] = t_; acc[1][j] = t_;                                          \
    }                                                                          \
  } while (0)

#define ACC_ADDB(bptr)                                                         \
  do {                                                                         \
    _Pragma("unroll") for (int j = 0; j < 4; ++j) {                            \
      float b_ = (bptr)[nBase + 16 * j];                                       \
      acc[0][j] += b_; acc[1][j] += b_;                                        \
    }                                                                          \
  } while (0)

#define GEMM(XB, XSTR, WSTR, NKT)                                              \
  do {                                                                         \
    _Pragma("unroll") for (int kt = 0; kt < (NKT); ++kt) {                     \
      bf16x8 a0 = *(const bf16x8*)(lds + (XB) + (32 * wr + li) * (XSTR) + kt * 64 + h16);      \
      bf16x8 a1 = *(const bf16x8*)(lds + (XB) + (32 * wr + 16 + li) * (XSTR) + kt * 64 + h16); \
      _Pragma("unroll") for (int j = 0; j < 4; ++j) {                          \
        bf16x8 bfr = *(const bf16x8*)(lds + LDS_W + (nBase + 16 * j) * (WSTR) + kt * 64 + h16);\
        acc[0][j] = __builtin_amdgcn_mfma_f32_16x16x32_bf16(a0, bfr, acc[0][j], 0, 0, 0);      \
        acc[1][j] = __builtin_amdgcn_mfma_f32_16x16x32_bf16(a1, bfr, acc[1][j], 0, 0, 0);      \
      }                                                                        \
    }                                                                          \
  } while (0)

#define STORE_X_RELU()                                                         \
  do {                                                                         \
    _Pragma("unroll") for (int mi = 0; mi < 2; ++mi)                           \
    _Pragma("unroll") for (int j = 0; j < 4; ++j)                              \
    _Pragma("unroll") for (int rr = 0; rr < 4; ++rr) {                         \
      float v_ = acc[mi][j][rr]; v_ = v_ > 0.f ? v_ : 0.f;                     \
      int m_ = 32 * wr + 16 * mi + 4 * h + rr;                                 \
      *(u16*)(lds + LDS_X + m_ * 272 + (nBase + 16 * j) * 2) = f2bf(v_);       \
    }                                                                          \
  } while (0)

__global__ void __launch_bounds__(256, 2) nerf_main(
    const float* __restrict__ coords, const float* __restrict__ condition,
    const float* __restrict__ ray_dir, const float* __restrict__ noise,
    const float* __restrict__ b_blocks, const float* __restrict__ W_out,
    const float* __restrict__ b_out, const float* __restrict__ W_rgb,
    const float* __restrict__ b_rgb, const char* __restrict__ ws,
    float* __restrict__ out) {
  __shared__ __align__(16) char lds[LDS_TOTAL];
  const int tid = threadIdx.x;
  const int lane = tid & 63;
  const int wv = tid >> 6;
  const int wr = wv >> 1, wc = wv & 1;
  const int li = lane & 15, h = lane >> 4;
  const int h16 = h * 16;
  const int p0 = blockIdx.x * 64;
  const int nBase = 64 * wc + li;

  // ---- stage condition: shape -> LDS_X (+reg stash), app -> reg stash ----
  u32 cshape[16], capp[16];
#pragma unroll
  for (int it = 0; it < 16; ++it) {
    const int j = it >> 1, half = it & 1;
    const int row = (tid >> 5) + 8 * j;
    const int col4 = (tid & 31) + 32 * half;
    float4 v = *(const float4*)(condition + (size_t)(p0 + row) * 256 + col4 * 4);
    u32 lo = pack2(v.x, v.y), hi = pack2(v.z, v.w);
    if (half == 0) {
      cshape[2 * j] = lo; cshape[2 * j + 1] = hi;
      uint2 t; t.x = lo; t.y = hi;
      *(uint2*)(lds + LDS_X + row * 272 + col4 * 8) = t;
    } else {
      capp[2 * j] = lo; capp[2 * j + 1] = hi;
    }
  }
  // ---- stage positional encoding -> LDS_XE ----
  {
    const int row = tid >> 2, sub = tid & 3;
    const float* cp = coords + (size_t)(p0 + row) * 3;
    float c0 = cp[0], c1 = cp[1], c2 = cp[2];
#pragma unroll
    for (int q2 = 0; q2 < 9; ++q2) {
      float va = enc_val3(c0, c1, c2, sub * 18 + 2 * q2, 63);
      float vb = enc_val3(c0, c1, c2, sub * 18 + 2 * q2 + 1, 63);
      *(u32*)(lds + LDS_XE + row * 144 + sub * 36 + q2 * 4) = pack2(va, vb);
    }
  }
  __syncthreads();

  f32x4 acc[2][4];

  // ---- layer 0: net = enc@W_in + cond_shape@W_c + (b_in+b_c) ----
  STAGEW(OFF_IN, 18432);
  __syncthreads();
  ACC_INIT((const float*)(ws + OFF_BIAS0));
  GEMM(LDS_XE, 144, 144, 2);
  __syncthreads();
  STAGEW(OFF_C, 34816);
  __syncthreads();
  GEMM(LDS_X, 272, 272, 4);
  STORE_X_RELU();  // in-place: each wave owns its rows

  // ---- 8 hidden blocks (skip added into acc at idx==3, i.e. onto net_4 pre-relu) ----
  for (int idx = 0; idx < 8; ++idx) {
    __syncthreads();
    STAGEW(OFF_B0 + (long)idx * 34816, 34816);
    __syncthreads();
    ACC_INIT(b_blocks + idx * 128);
    GEMM(LDS_X, 272, 272, 4);
    if (idx == 3) {
      __syncthreads();
      STAGEW(OFF_SKIP, 18432);
      // rewrite cond_shape into LDS_X (X3 no longer needed)
#pragma unroll
      for (int j2 = 0; j2 < 8; ++j2) {
        int row = (tid >> 5) + 8 * j2;
        uint2 t; t.x = cshape[2 * j2]; t.y = cshape[2 * j2 + 1];
        *(uint2*)(lds + LDS_X + row * 272 + (tid & 31) * 8) = t;
      }
      __syncthreads();
      GEMM(LDS_XE, 144, 144, 2);
      ACC_ADDB((const float*)(ws + OFF_BIASSK));
      __syncthreads();
      STAGEW(OFF_SKIPC, 34816);
      __syncthreads();
      GEMM(LDS_X, 272, 272, 4);
    }
    if (idx < 7) STORE_X_RELU();
  }

  // ---- sigma = relu( relu(net8)@W_out + b_out + noise ) ----
  {
    float wout[4];
#pragma unroll
    for (int j = 0; j < 4; ++j) wout[j] = W_out[nBase + 16 * j];
    float* sp = (float*)(lds + LDS_XE);
#pragma unroll
    for (int mi = 0; mi < 2; ++mi)
#pragma unroll
      for (int rr = 0; rr < 4; ++rr) {
        float s = 0.f;
#pragma unroll
        for (int j = 0; j < 4; ++j) {
          float v = acc[mi][j][rr]; v = v > 0.f ? v : 0.f;
          s += v * wout[j];
        }
        s += __shfl_xor(s, 1); s += __shfl_xor(s, 2);
        s += __shfl_xor(s, 4); s += __shfl_xor(s, 8);
        if (li == 0) sp[(32 * wr + 16 * mi + 4 * h + rr) * 2 + wc] = s;
      }
    __syncthreads();
    if (tid < 64) {
      float s = sp[2 * tid] + sp[2 * tid + 1] + b_out[0] + noise[p0 + tid];
      out[(size_t)(p0 + tid) * 4] = s > 0.f ? s : 0.f;
    }
    __syncthreads();
  }

  // ---- view branch: acc += enc_v@W_view + cond_app@W_viewc + (b_view+b_viewc) ----
  // cond_app -> LDS_X
#pragma unroll
  for (int j2 = 0; j2 < 8; ++j2) {
    int row = (tid >> 5) + 8 * j2;
    uint2 t; t.x = capp[2 * j2]; t.y = capp[2 * j2 + 1];
    *(uint2*)(lds + LDS_X + row * 272 + (tid & 31) * 8) = t;
  }
  // enc_v -> LDS_XE ([64][40] bf16, stride 80B)
  {
    const int row = tid >> 2, sub = tid & 3;
    const float* rp_ = ray_dir + (size_t)(p0 + row) * 3;
    float r0 = rp_[0], r1 = rp_[1], r2 = rp_[2];
    float inv = 1.f / sqrtf(r0 * r0 + r1 * r1 + r2 * r2);
    r0 *= inv; r1 *= inv; r2 *= inv;
#pragma unroll
    for (int q2 = 0; q2 < 5; ++q2) {
      float va = enc_val3(r0, r1, r2, sub * 10 + 2 * q2, 27);
      float vb = enc_val3(r0, r1, r2, sub * 10 + 2 * q2 + 1, 27);
      *(u32*)(lds + LDS_XE + row * 80 + sub * 20 + q2 * 4) = pack2(va, vb);
    }
  }
  STAGEW(OFF_VIEW, 10240);
  __syncthreads();
  ACC_ADDB((const float*)(ws + OFF_BIASV));
  GEMM(LDS_XE, 80, 80, 1);
  __syncthreads();
  STAGEW(OFF_VIEWC, 34816);
  __syncthreads();
  GEMM(LDS_X, 272, 272, 4);

  // ---- rgb = sigmoid( relu(net_v)@W_rgb + b_rgb ) ----
  {
    float wrgb[4][3];
#pragma unroll
    for (int j = 0; j < 4; ++j) {
      int n = nBase + 16 * j;
      wrgb[j][0] = W_rgb[n * 3 + 0];
      wrgb[j][1] = W_rgb[n * 3 + 1];
      wrgb[j][2] = W_rgb[n * 3 + 2];
    }
    float* rp = (float*)(lds + LDS_XE + 5120);
#pragma unroll
    for (int mi = 0; mi < 2; ++mi)
#pragma unroll
      for (int rr = 0; rr < 4; ++rr) {
        float s0 = 0.f, s1 = 0.f, s2 = 0.f;
#pragma unroll
        for (int j = 0; j < 4; ++j) {
          float v = acc[mi][j][rr]; v = v > 0.f ? v : 0.f;
          s0 += v * wrgb[j][0]; s1 += v * wrgb[j][1]; s2 += v * wrgb[j][2];
        }
        s0 += __shfl_xor(s0, 1); s0 += __shfl_xor(s0, 2); s0 += __shfl_xor(s0, 4); s0 += __shfl_xor(s0, 8);
        s1 += __shfl_xor(s1, 1); s1 += __shfl_xor(s1, 2); s1 += __shfl_xor(s1, 4); s1 += __shfl_xor(s1, 8);
        s2 += __shfl_xor(s2, 1); s2 += __shfl_xor(s2, 2); s2 += __shfl_xor(s2, 4); s2 += __shfl_xor(s2, 8);
        if (li == 0) {
          int m = 32 * wr + 16 * mi + 4 * h + rr;
          rp[(m * 2 + wc) * 3 + 0] = s0;
          rp[(m * 2 + wc) * 3 + 1] = s1;
          rp[(m * 2 + wc) * 3 + 2] = s2;
        }
      }
    __syncthreads();
    if (tid < 64) {
#pragma unroll
      for (int c = 0; c < 3; ++c) {
        float v = rp[tid * 6 + c] + rp[tid * 6 + 3 + c] + b_rgb[c];
        out[(size_t)(p0 + tid) * 4 + 1 + c] = 1.f / (1.f + expf(-v));
      }
    }
  }
}

extern "C" void kernel_launch(void* const* d_in, const int* in_sizes, int n_in,
                              void* d_out, int out_size, void* d_ws, size_t ws_size,
                              hipStream_t stream) {
  const float* coords    = (const float*)d_in[0];
  const float* condition = (const float*)d_in[1];
  const float* ray_dir   = (const float*)d_in[2];
  const float* noise     = (const float*)d_in[3];
  const float* W_in      = (const float*)d_in[4];
  const float* b_in      = (const float*)d_in[5];
  const float* W_blocks  = (const float*)d_in[6];
  const float* b_blocks  = (const float*)d_in[7];
  const float* W_c       = (const float*)d_in[8];
  const float* b_c       = (const float*)d_in[9];
  const float* W_skip    = (const float*)d_in[10];
  const float* b_skip    = (const float*)d_in[11];
  const float* W_skipc   = (const float*)d_in[12];
  const float* b_skipc   = (const float*)d_in[13];
  const float* W_out     = (const float*)d_in[14];
  const float* b_out     = (const float*)d_in[15];
  const float* W_viewc   = (const float*)d_in[16];
  const float* b_viewc   = (const float*)d_in[17];
  const float* W_view    = (const float*)d_in[18];
  const float* b_view    = (const float*)d_in[19];
  const float* W_rgb     = (const float*)d_in[20];
  const float* b_rgb     = (const float*)d_in[21];
  char* ws = (char*)d_ws;
  float* out = (float*)d_out;

  prep_kernel<<<842, 256, 0, stream>>>(W_in, W_c, W_blocks, W_skip, W_skipc, W_view, W_viewc,
                                       b_in, b_c, b_skip, b_skipc, b_view, b_viewc, ws);
  nerf_main<<<4096, 256, 0, stream>>>(coords, condition, ray_dir, noise,
                                      b_blocks, W_out, b_out, W_rgb, b_rgb, ws, out);
}

// Round 2
// 280.581 us; speedup vs baseline: 1.6299x; 1.6299x over previous
//
#include <hip/hip_runtime.h>
#include <hip/hip_bf16.h>

typedef unsigned int u32;
typedef unsigned short u16;

using bf16x8 = __attribute__((ext_vector_type(8))) short;
using f32x4  = __attribute__((ext_vector_type(4))) float;

// ---------------- workspace layout (bytes) — same as round 1 ----------------
#define OFF_IN     0L        // Wt_in   [128][72]  bf16 = 18432
#define OFF_C      18432L    // Wt_c    [128][136] bf16 = 34816
#define OFF_B0     53248L    // Wt_b[8] [128][136] bf16 = 8*34816
#define OFF_SKIP   331776L   // Wt_skip [128][72]
#define OFF_SKIPC  350208L   // Wt_skipc[128][136]
#define OFF_VIEW   385024L   // Wt_view [128][40] = 10240
#define OFF_VIEWC  395264L   // Wt_viewc[128][136]
#define OFF_BIAS0  430080L   // f32[128] b_in+b_c
#define OFF_BIASSK 430592L   // f32[128] b_skip+b_skipc
#define OFF_BIASV  431104L   // f32[128] b_view+b_viewc

// ---------------- LDS layout (bytes) ----------------
#define LDS_X   0        // activations [256][136] bf16, stride 272B = 69632
#define LDS_W   69632    // weight double buffer: 2 x [128][<=136] = 2*34816
#define LDS_SP  139264   // sigma partials [256][2] f32 = 2048
#define LDS_RP  141312   // rgb partials [256][2][3] f32 = 6144
#define LDS_TOTAL 147456

__device__ __forceinline__ u16 f2bf(float x) {
  union { float f; u32 u; } un; un.f = x;
  u32 u = un.u;
  return (u16)((u + 0x7fffu + ((u >> 16) & 1u)) >> 16);
}
__device__ __forceinline__ u32 pack2(float a, float b) {
  return (u32)f2bf(a) | ((u32)f2bf(b) << 16);
}
__device__ __forceinline__ float sel3(float a, float b, float c, int i) {
  return i == 0 ? a : (i == 1 ? b : c);
}
__device__ __forceinline__ float enc_val3(float a, float b, float c, int e, int kreal) {
  if (e >= kreal) return 0.f;
  if (e < 3) return sel3(a, b, c, e);
  int t = e - 3;
  int l = t / 6;
  int rem = t - l * 6;
  int pi = rem >= 3 ? rem - 3 : rem;
  float x = sel3(a, b, c, pi) * (float)(1 << l);
  return rem < 3 ? __sinf(x) : __cosf(x);
}
__device__ __forceinline__ bf16x8 mk8(u32 a, u32 b, u32 c, u32 d) {
  union { u32 u[4]; bf16x8 v; } t; t.u[0] = a; t.u[1] = b; t.u[2] = c; t.u[3] = d;
  return t.v;
}

// ---------------- prep kernel (unchanged from round 1) ----------------
__global__ void prep_kernel(
    const float* __restrict__ Win, const float* __restrict__ Wc, const float* __restrict__ Wb,
    const float* __restrict__ Wskip, const float* __restrict__ Wskipc,
    const float* __restrict__ Wview, const float* __restrict__ Wviewc,
    const float* __restrict__ bin, const float* __restrict__ bc,
    const float* __restrict__ bskip, const float* __restrict__ bskipc,
    const float* __restrict__ bview, const float* __restrict__ bviewc,
    char* __restrict__ ws) {
  int i = blockIdx.x * 256 + threadIdx.x;
  if (i >= 215424) return;
  int r = i;
  const float* src; int kpad, kreal; long dstoff;
  if (r < 9216)                    { src = Win;    kpad = 72;  kreal = 63;  dstoff = OFF_IN; }
  else if ((r -= 9216) < 17408)    { src = Wc;     kpad = 136; kreal = 128; dstoff = OFF_C; }
  else if ((r -= 17408) < 139264)  { int b = r / 17408; r -= b * 17408;
                                     src = Wb + (long)b * 16384; kpad = 136; kreal = 128;
                                     dstoff = OFF_B0 + (long)b * 34816; }
  else if ((r -= 139264) < 9216)   { src = Wskip;  kpad = 72;  kreal = 63;  dstoff = OFF_SKIP; }
  else if ((r -= 9216) < 17408)    { src = Wskipc; kpad = 136; kreal = 128; dstoff = OFF_SKIPC; }
  else if ((r -= 17408) < 5120)    { src = Wview;  kpad = 40;  kreal = 27;  dstoff = OFF_VIEW; }
  else if ((r -= 5120) < 17408)    { src = Wviewc; kpad = 136; kreal = 128; dstoff = OFF_VIEWC; }
  else {
    r -= 17408;
    int which = r >> 7, n = r & 127;
    const float* A  = which == 0 ? bin : (which == 1 ? bskip : bview);
    const float* Bp = which == 0 ? bc  : (which == 1 ? bskipc : bviewc);
    long off = which == 0 ? OFF_BIAS0 : (which == 1 ? OFF_BIASSK : OFF_BIASV);
    *(float*)(ws + off + (long)n * 4) = A[n] + Bp[n];
    return;
  }
  int n = r / kpad, k = r - n * kpad;
  float v = (k < kreal) ? src[(long)k * 128 + n] : 0.f;
  *(u16*)(ws + dstoff + ((long)n * kpad + k) * 2) = f2bf(v);
}

// ---------------- staging macros (T14 async split: load early, write late) ----------------
#define STG_LD(off, bytes)                                                     \
  do {                                                                         \
    _Pragma("unroll") for (int k_ = 0; k_ < 5; ++k_) {                         \
      if (k_ * 512 * 16 < (bytes)) {                                           \
        int u_ = tid + k_ * 512;                                               \
        if ((long)u_ * 16 < (bytes))                                           \
          stg[k_] = *(const int4*)(ws + (off) + (long)u_ * 16);                \
      }                                                                        \
    }                                                                          \
  } while (0)

#define STG_WR(bytes, b)                                                       \
  do {                                                                         \
    _Pragma("unroll") for (int k_ = 0; k_ < 5; ++k_) {                         \
      if (k_ * 512 * 16 < (bytes)) {                                           \
        int u_ = tid + k_ * 512;                                               \
        if ((long)u_ * 16 < (bytes))                                           \
          *(int4*)(lds + LDS_W + (b) * 34816 + (long)u_ * 16) = stg[k_];       \
      }                                                                        \
    }                                                                          \
  } while (0)

#define STG_DIRECT(off, bytes, b)                                              \
  do {                                                                         \
    _Pragma("unroll") for (int k_ = 0; k_ < 5; ++k_) {                         \
      if (k_ * 512 * 16 < (bytes)) {                                           \
        int u_ = tid + k_ * 512;                                               \
        if ((long)u_ * 16 < (bytes))                                           \
          *(int4*)(lds + LDS_W + (b) * 34816 + (long)u_ * 16) =                \
              *(const int4*)(ws + (off) + (long)u_ * 16);                      \
      }                                                                        \
    }                                                                          \
  } while (0)

// ---------------- GEMM macros (swapped operands: D[lane&15] = point-row) ----------------
// acc[mi][j]: m = 64*wr+16*mi+li (lane li), n = 64*wc+16*j+4*h+rr (reg rr)
#define GEMM_X(WBASE, NKT)                                                     \
  do {                                                                         \
    _Pragma("unroll") for (int kt = 0; kt < (NKT); ++kt) {                     \
      bf16x8 xf[4];                                                            \
      _Pragma("unroll") for (int mi = 0; mi < 4; ++mi)                         \
        xf[mi] = *(const bf16x8*)(lds + LDS_X + (64*wr + 16*mi + li) * 272 + kt * 64 + h16); \
      _Pragma("unroll") for (int j = 0; j < 4; ++j) {                          \
        bf16x8 wf = *(const bf16x8*)(lds + (WBASE) + (64*wc + 16*j + li) * 272 + kt * 64 + h16); \
        _Pragma("unroll") for (int mi = 0; mi < 4; ++mi)                       \
          acc[mi][j] = __builtin_amdgcn_mfma_f32_16x16x32_bf16(wf, xf[mi], acc[mi][j], 0, 0, 0); \
      }                                                                        \
    }                                                                          \
  } while (0)

#define GEMM_E(WBASE, WSTR, NKT, EF)                                           \
  do {                                                                         \
    _Pragma("unroll") for (int kt = 0; kt < (NKT); ++kt) {                     \
      _Pragma("unroll") for (int j = 0; j < 4; ++j) {                          \
        bf16x8 wf = *(const bf16x8*)(lds + (WBASE) + (64*wc + 16*j + li) * (WSTR) + kt * 64 + h16); \
        _Pragma("unroll") for (int mi = 0; mi < 4; ++mi)                       \
          acc[mi][j] = __builtin_amdgcn_mfma_f32_16x16x32_bf16(wf, (EF)[mi][kt], acc[mi][j], 0, 0, 0); \
      }                                                                        \
    }                                                                          \
  } while (0)

#define ACC_SET(bptr)                                                          \
  do {                                                                         \
    _Pragma("unroll") for (int j = 0; j < 4; ++j) {                            \
      f32x4 b4_ = *(const f32x4*)((bptr) + 64*wc + 16*j + 4*h);                \
      _Pragma("unroll") for (int mi = 0; mi < 4; ++mi) acc[mi][j] = b4_;       \
    }                                                                          \
  } while (0)

#define ACC_ADD(bptr)                                                          \
  do {                                                                         \
    _Pragma("unroll") for (int j = 0; j < 4; ++j) {                            \
      f32x4 b4_ = *(const f32x4*)((bptr) + 64*wc + 16*j + 4*h);                \
      _Pragma("unroll") for (int mi = 0; mi < 4; ++mi) acc[mi][j] += b4_;      \
    }                                                                          \
  } while (0)

#define STORE_X()                                                              \
  do {                                                                         \
    _Pragma("unroll") for (int mi = 0; mi < 4; ++mi)                           \
    _Pragma("unroll") for (int j = 0; j < 4; ++j) {                            \
      f32x4 v_ = acc[mi][j];                                                   \
      uint2 t_;                                                                \
      t_.x = pack2(fmaxf(v_[0], 0.f), fmaxf(v_[1], 0.f));                      \
      t_.y = pack2(fmaxf(v_[2], 0.f), fmaxf(v_[3], 0.f));                      \
      *(uint2*)(lds + LDS_X + (64*wr + 16*mi + li) * 272 + (64*wc + 16*j + 4*h) * 2) = t_; \
    }                                                                          \
  } while (0)

#define APP_LOAD(c)                                                            \
  f32x4 af##c[4];                                                              \
  do {                                                                         \
    _Pragma("unroll") for (int i2 = 0; i2 < 4; ++i2) {                         \
      int f4i = (4*(c) + i2) * 512 + tid;                                      \
      int row = f4i >> 5, c4i = f4i & 31;                                      \
      af##c[i2] = *(const f32x4*)(condition + (size_t)(p0 + row) * 256 + (32 + c4i) * 4); \
    }                                                                          \
  } while (0)

#define APP_PACK(c)                                                            \
  do {                                                                         \
    _Pragma("unroll") for (int i2 = 0; i2 < 4; ++i2) {                         \
      int i_ = 4*(c) + i2;                                                     \
      appst[2*i_]   = pack2(af##c[i2][0], af##c[i2][1]);                       \
      appst[2*i_+1] = pack2(af##c[i2][2], af##c[i2][3]);                       \
    }                                                                          \
  } while (0)

__global__ void __launch_bounds__(512, 2) nerf_main(
    const float* __restrict__ coords, const float* __restrict__ condition,
    const float* __restrict__ ray_dir, const float* __restrict__ noise,
    const float* __restrict__ b_blocks, const float* __restrict__ W_out,
    const float* __restrict__ b_out, const float* __restrict__ W_rgb,
    const float* __restrict__ b_rgb, const char* __restrict__ ws,
    float* __restrict__ out) {
  extern __shared__ __align__(16) char lds[];
  const int tid = threadIdx.x;
  const int lane = tid & 63;
  const int wv = tid >> 6;          // 8 waves
  const int wr = wv >> 1, wc = wv & 1;
  const int li = lane & 15, h = lane >> 4;
  const int h16 = h * 16;
  const int p0 = blockIdx.x * 256;

  int4 stg[5];
  f32x4 acc[4][4];

  // ==== prologue: issue cond_shape loads ====
  f32x4 sh[16];
#pragma unroll
  for (int i = 0; i < 16; ++i) {
    int f4i = i * 512 + tid;
    int row = f4i >> 5, c4i = f4i & 31;
    sh[i] = *(const f32x4*)(condition + (size_t)(p0 + row) * 256 + c4i * 4);
  }
  // enc fragments in registers: rows 64*wr+16*mi+li, k = 32*kt+8*h+e
  bf16x8 encf[4][2];
#pragma unroll
  for (int mi = 0; mi < 4; ++mi) {
    int r = 64 * wr + 16 * mi + li;
    const float* cp = coords + (size_t)(p0 + r) * 3;
    float c0 = cp[0], c1 = cp[1], c2 = cp[2];
#pragma unroll
    for (int kt = 0; kt < 2; ++kt) {
      u32 w[4];
#pragma unroll
      for (int e2 = 0; e2 < 4; ++e2) {
        int k0 = kt * 32 + h * 8 + e2 * 2;
        w[e2] = pack2(enc_val3(c0, c1, c2, k0, 63), enc_val3(c0, c1, c2, k0 + 1, 63));
      }
      encf[mi][kt] = mk8(w[0], w[1], w[2], w[3]);
    }
  }
  // stage Win -> buf0
  STG_DIRECT(OFF_IN, 18432, 0);
  // pack shape -> stash, write to X
  u32 stash[32];
#pragma unroll
  for (int i = 0; i < 16; ++i) {
    stash[2*i]   = pack2(sh[i][0], sh[i][1]);
    stash[2*i+1] = pack2(sh[i][2], sh[i][3]);
    int f4i = i * 512 + tid;
    int row = f4i >> 5, c4i = f4i & 31;
    uint2 t; t.x = stash[2*i]; t.y = stash[2*i+1];
    *(uint2*)(lds + LDS_X + row * 272 + c4i * 8) = t;
  }
  __syncthreads();

  // ==== P0: Win (buf0, stride 144, kt2, enc regs) ====
  STG_LD(OFF_C, 34816);
  ACC_SET((const float*)(ws + OFF_BIAS0));
  GEMM_E(LDS_W + 0 * 34816, 144, 2, encf);
  STG_WR(34816, 1);
  __syncthreads();

  // ==== P1: Wc (buf1, X=shape) ====
  STG_LD(OFF_B0 + 0L * 34816, 34816);
  GEMM_X(LDS_W + 1 * 34816, 4);
  STG_WR(34816, 0);
  __syncthreads();
  STORE_X();
  __syncthreads();

  // ==== P2-P5: Wb0..Wb3 ====
  // P2 (buf0)
  STG_LD(OFF_B0 + 1L * 34816, 34816);
  ACC_SET(b_blocks + 0 * 128);
  GEMM_X(LDS_W + 0 * 34816, 4);
  STG_WR(34816, 1);
  __syncthreads();
  STORE_X();
  __syncthreads();
  // P3 (buf1)
  STG_LD(OFF_B0 + 2L * 34816, 34816);
  ACC_SET(b_blocks + 1 * 128);
  GEMM_X(LDS_W + 1 * 34816, 4);
  STG_WR(34816, 0);
  __syncthreads();
  STORE_X();
  __syncthreads();
  // P4 (buf0)
  STG_LD(OFF_B0 + 3L * 34816, 34816);
  ACC_SET(b_blocks + 2 * 128);
  GEMM_X(LDS_W + 0 * 34816, 4);
  STG_WR(34816, 1);
  __syncthreads();
  STORE_X();
  __syncthreads();
  // P5 (buf1) — no store (skip gets added before relu)
  STG_LD(OFF_SKIP, 18432);
  ACC_SET(b_blocks + 3 * 128);
  GEMM_X(LDS_W + 1 * 34816, 4);
  STG_WR(18432, 0);
  __syncthreads();

  // ==== P6: Wskip (buf0, stride 144, kt2, enc regs); rewrite X = cond_shape ====
  STG_LD(OFF_SKIPC, 34816);
  ACC_ADD((const float*)(ws + OFF_BIASSK));
  GEMM_E(LDS_W + 0 * 34816, 144, 2, encf);
  STG_WR(34816, 1);
#pragma unroll
  for (int i = 0; i < 16; ++i) {
    int f4i = i * 512 + tid;
    int row = f4i >> 5, c4i = f4i & 31;
    uint2 t; t.x = stash[2*i]; t.y = stash[2*i+1];
    *(uint2*)(lds + LDS_X + row * 272 + c4i * 8) = t;
  }
  __syncthreads();

  // ==== P7: Wskipc (buf1, X=shape) ====
  STG_LD(OFF_B0 + 4L * 34816, 34816);
  GEMM_X(LDS_W + 1 * 34816, 4);
  STG_WR(34816, 0);
  __syncthreads();
  STORE_X();
  __syncthreads();

  u32 appst[32];
  // ==== P8: Wb4 (buf0) + app chunk0 ====
  STG_LD(OFF_B0 + 5L * 34816, 34816);
  APP_LOAD(0);
  ACC_SET(b_blocks + 4 * 128);
  GEMM_X(LDS_W + 0 * 34816, 4);
  STG_WR(34816, 1);
  APP_PACK(0);
  __syncthreads();
  STORE_X();
  __syncthreads();
  // ==== P9: Wb5 (buf1) + app chunk1 ====
  STG_LD(OFF_B0 + 6L * 34816, 34816);
  APP_LOAD(1);
  ACC_SET(b_blocks + 5 * 128);
  GEMM_X(LDS_W + 1 * 34816, 4);
  STG_WR(34816, 0);
  APP_PACK(1);
  __syncthreads();
  STORE_X();
  __syncthreads();
  // ==== P10: Wb6 (buf0) + app chunk2 + ray loads ====
  STG_LD(OFF_B0 + 7L * 34816, 34816);
  APP_LOAD(2);
  float ray0[4], ray1[4], ray2[4];
#pragma unroll
  for (int mi = 0; mi < 4; ++mi) {
    size_t base = (size_t)(p0 + 64 * wr + 16 * mi + li) * 3;
    ray0[mi] = ray_dir[base]; ray1[mi] = ray_dir[base + 1]; ray2[mi] = ray_dir[base + 2];
  }
  ACC_SET(b_blocks + 6 * 128);
  GEMM_X(LDS_W + 0 * 34816, 4);
  STG_WR(34816, 1);
  APP_PACK(2);
  __syncthreads();
  STORE_X();
  __syncthreads();
  // ==== P11: Wb7 (buf1) + app chunk3 + noise; sigma partials ====
  STG_LD(OFF_VIEW, 10240);
  APP_LOAD(3);
  float nz = 0.f;
  if (tid < 256) nz = noise[p0 + tid];
  ACC_SET(b_blocks + 7 * 128);
  GEMM_X(LDS_W + 1 * 34816, 4);
  STG_WR(10240, 0);
  APP_PACK(3);
  {
    f32x4 wo[4];
#pragma unroll
    for (int j = 0; j < 4; ++j) wo[j] = *(const f32x4*)(W_out + 64 * wc + 16 * j + 4 * h);
#pragma unroll
    for (int mi = 0; mi < 4; ++mi) {
      float s = 0.f;
#pragma unroll
      for (int j = 0; j < 4; ++j)
#pragma unroll
        for (int rr = 0; rr < 4; ++rr) s += fmaxf(acc[mi][j][rr], 0.f) * wo[j][rr];
      s += __shfl_xor(s, 16); s += __shfl_xor(s, 32);
      if (h == 0) *(float*)(lds + LDS_SP + ((64 * wr + 16 * mi + li) * 2 + wc) * 4) = s;
    }
  }
  __syncthreads();

  // ==== P12: Wview (buf0, stride 80, kt1, encv regs); rewrite X=app; sigma combine ====
  STG_LD(OFF_VIEWC, 34816);
  bf16x8 envf[4][1];
#pragma unroll
  for (int mi = 0; mi < 4; ++mi) {
    float r0 = ray0[mi], r1 = ray1[mi], r2 = ray2[mi];
    float inv = 1.f / sqrtf(r0 * r0 + r1 * r1 + r2 * r2);
    r0 *= inv; r1 *= inv; r2 *= inv;
    u32 w[4];
#pragma unroll
    for (int e2 = 0; e2 < 4; ++e2) {
      int k0 = h * 8 + e2 * 2;
      w[e2] = pack2(enc_val3(r0, r1, r2, k0, 27), enc_val3(r0, r1, r2, k0 + 1, 27));
    }
    envf[mi][0] = mk8(w[0], w[1], w[2], w[3]);
  }
  ACC_ADD((const float*)(ws + OFF_BIASV));
  GEMM_E(LDS_W + 0 * 34816, 80, 1, envf);
  STG_WR(34816, 1);
#pragma unroll
  for (int i = 0; i < 16; ++i) {
    int f4i = i * 512 + tid;
    int row = f4i >> 5, c4i = f4i & 31;
    uint2 t; t.x = appst[2*i]; t.y = appst[2*i+1];
    *(uint2*)(lds + LDS_X + row * 272 + c4i * 8) = t;
  }
  float sig = 0.f;
  if (tid < 256) {
    const float* sp = (const float*)(lds + LDS_SP);
    float s = sp[2 * tid] + sp[2 * tid + 1] + b_out[0] + nz;
    sig = fmaxf(s, 0.f);
  }
  __syncthreads();

  // ==== P13: Wviewc (buf1, X=app); rgb ====
  GEMM_X(LDS_W + 1 * 34816, 4);
  {
#pragma unroll
    for (int mi = 0; mi < 4; ++mi) {
      float s0 = 0.f, s1 = 0.f, s2 = 0.f;
#pragma unroll
      for (int j = 0; j < 4; ++j)
#pragma unroll
        for (int rr = 0; rr < 4; ++rr) {
          float v = fmaxf(acc[mi][j][rr], 0.f);
          int n = 64 * wc + 16 * j + 4 * h + rr;
          s0 += v * W_rgb[n * 3 + 0];
          s1 += v * W_rgb[n * 3 + 1];
          s2 += v * W_rgb[n * 3 + 2];
        }
      s0 += __shfl_xor(s0, 16); s0 += __shfl_xor(s0, 32);
      s1 += __shfl_xor(s1, 16); s1 += __shfl_xor(s1, 32);
      s2 += __shfl_xor(s2, 16); s2 += __shfl_xor(s2, 32);
      if (h == 0) {
        float* rp = (float*)(lds + LDS_RP);
        int m_ = 64 * wr + 16 * mi + li;
        rp[(m_ * 2 + wc) * 3 + 0] = s0;
        rp[(m_ * 2 + wc) * 3 + 1] = s1;
        rp[(m_ * 2 + wc) * 3 + 2] = s2;
      }
    }
  }
  __syncthreads();
  if (tid < 256) {
    const float* rp = (const float*)(lds + LDS_RP);
    f32x4 o4;
    o4[0] = sig;
#pragma unroll
    for (int c = 0; c < 3; ++c) {
      float v = rp[(2 * tid) * 3 + c] + rp[(2 * tid + 1) * 3 + c] + b_rgb[c];
      o4[1 + c] = 1.f / (1.f + __expf(-v));
    }
    *(f32x4*)(out + (size_t)(p0 + tid) * 4) = o4;
  }
}

extern "C" void kernel_launch(void* const* d_in, const int* in_sizes, int n_in,
                              void* d_out, int out_size, void* d_ws, size_t ws_size,
                              hipStream_t stream) {
  const float* coords    = (const float*)d_in[0];
  const float* condition = (const float*)d_in[1];
  const float* ray_dir   = (const float*)d_in[2];
  const float* noise     = (const float*)d_in[3];
  const float* W_in      = (const float*)d_in[4];
  const float* b_in      = (const float*)d_in[5];
  const float* W_blocks  = (const float*)d_in[6];
  const float* b_blocks  = (const float*)d_in[7];
  const float* W_c       = (const float*)d_in[8];
  const float* b_c       = (const float*)d_in[9];
  const float* W_skip    = (const float*)d_in[10];
  const float* b_skip    = (const float*)d_in[11];
  const float* W_skipc   = (const float*)d_in[12];
  const float* b_skipc   = (const float*)d_in[13];
  const float* W_out     = (const float*)d_in[14];
  const float* b_out     = (const float*)d_in[15];
  const float* W_viewc   = (const float*)d_in[16];
  const float* b_viewc   = (const float*)d_in[17];
  const float* W_view    = (const float*)d_in[18];
  const float* b_view    = (const float*)d_in[19];
  const float* W_rgb     = (const float*)d_in[20];
  const float* b_rgb     = (const float*)d_in[21];
  char* ws = (char*)d_ws;
  float* out = (float*)d_out;

  prep_kernel<<<842, 256, 0, stream>>>(W_in, W_c, W_blocks, W_skip, W_skipc, W_view, W_viewc,
                                       b_in, b_c, b_skip, b_skipc, b_view, b_viewc, ws);
  nerf_main<<<1024, 512, LDS_TOTAL, stream>>>(coords, condition, ray_dir, noise,
                                              b_blocks, W_out, b_out, W_rgb, b_rgb, ws, out);
}